// Round 1
// baseline (496.105 us; speedup 1.0000x reference)
//
#include <hip/hip_runtime.h>
#include <math.h>

#define B_ 8
#define N_ 16384
#define G_ 128      // NUM_GROUPS
#define GS_ 32      // GROUP_SIZE
#define UK_ 128     // UPSCALE_K
#define FPS_T 1024
#define PPT 16      // points per thread in FPS (16*1024 = 16384)
#define BQ_T 256

// Exact-rounding distance^2, matching numpy: ((dx*dx + dy*dy) + dz*dz), no FMA.
__device__ __forceinline__ float dist2(float x, float y, float z,
                                       float cx, float cy, float cz) {
    float dx = __fsub_rn(x, cx);
    float dy = __fsub_rn(y, cy);
    float dz = __fsub_rn(z, cz);
    return __fadd_rn(__fadd_rn(__fmul_rn(dx, dx), __fmul_rn(dy, dy)),
                     __fmul_rn(dz, dz));
}

// ---------------------------------------------------------------------------
// Kernel 1: FPS (one block per batch) + fused cluster-NMS (wave 0 at the end).
// ---------------------------------------------------------------------------
__global__ __launch_bounds__(FPS_T) void fps_cnms_kernel(
    const float4* __restrict__ pts, const int* __restrict__ lengths,
    float* __restrict__ centers_out, int* __restrict__ keep_out) {
    const int b = blockIdx.x;
    const int t = threadIdx.x;
    const int lane = t & 63;
    const int wv = t >> 6;
    const int len = lengths[b];
    const float4* p = pts + (size_t)b * N_;

    // Register-resident point coords + running min-distance.
    float xs[PPT], ys[PPT], zs[PPT], mind[PPT];
#pragma unroll
    for (int i = 0; i < PPT; i++) {
        int n = i * FPS_T + t;
        float4 q = p[n];
        xs[i] = q.x; ys[i] = q.y; zs[i] = q.z;
        mind[i] = (n < len) ? INFINITY : -INFINITY;
    }

    __shared__ float s_part[16][5];   // per-wave (val, idx, x, y, z)
    __shared__ float s_bc[4];         // broadcast: idx(bits), x, y, z
    __shared__ float s_cen[G_][3];    // centers for CNMS

    if (t == 0) {
        float4 q = p[0];
        s_bc[0] = __int_as_float(0);
        s_bc[1] = q.x; s_bc[2] = q.y; s_bc[3] = q.z;
    }
    __syncthreads();

    for (int k = 0; k < G_; k++) {
        float cx = s_bc[1], cy = s_bc[2], cz = s_bc[3];
        if (t == 0) {
            centers_out[(b * G_ + k) * 3 + 0] = cx;
            centers_out[(b * G_ + k) * 3 + 1] = cy;
            centers_out[(b * G_ + k) * 3 + 2] = cz;
            s_cen[k][0] = cx; s_cen[k][1] = cy; s_cen[k][2] = cz;
        }

        // Local update + argmax tracking (strict > keeps earliest i => smallest n).
        float bv = -INFINITY, bx = 0.f, by = 0.f, bz = 0.f;
        int bn = 0x7fffffff;
#pragma unroll
        for (int i = 0; i < PPT; i++) {
            float d = dist2(xs[i], ys[i], zs[i], cx, cy, cz);
            float m = fminf(mind[i], d);   // invalid stays -inf
            mind[i] = m;
            bool tk = m > bv;
            bv = tk ? m : bv;
            bn = tk ? (i * FPS_T + t) : bn;
            bx = tk ? xs[i] : bx;
            by = tk ? ys[i] : by;
            bz = tk ? zs[i] : bz;
        }
        // Wave butterfly argmax: larger val wins; tie -> smaller index.
#pragma unroll
        for (int off = 32; off; off >>= 1) {
            float ov = __shfl_xor(bv, off);
            int   on = __shfl_xor(bn, off);
            float ox = __shfl_xor(bx, off);
            float oy = __shfl_xor(by, off);
            float oz = __shfl_xor(bz, off);
            bool tk = (ov > bv) || (ov == bv && on < bn);
            bv = tk ? ov : bv; bn = tk ? on : bn;
            bx = tk ? ox : bx; by = tk ? oy : by; bz = tk ? oz : bz;
        }
        if (lane == 0) {
            s_part[wv][0] = bv;
            s_part[wv][1] = __int_as_float(bn);
            s_part[wv][2] = bx; s_part[wv][3] = by; s_part[wv][4] = bz;
        }
        __syncthreads();
        if (wv == 0) {
            float v = (lane < 16) ? s_part[lane][0] : -INFINITY;
            int   n2 = (lane < 16) ? __float_as_int(s_part[lane][1]) : 0x7fffffff;
            float x2 = (lane < 16) ? s_part[lane][2] : 0.f;
            float y2 = (lane < 16) ? s_part[lane][3] : 0.f;
            float z2 = (lane < 16) ? s_part[lane][4] : 0.f;
#pragma unroll
            for (int off = 8; off; off >>= 1) {
                float ov = __shfl_xor(v, off);
                int   on = __shfl_xor(n2, off);
                float ox = __shfl_xor(x2, off);
                float oy = __shfl_xor(y2, off);
                float oz = __shfl_xor(z2, off);
                bool tk = (ov > v) || (ov == v && on < n2);
                v = tk ? ov : v; n2 = tk ? on : n2;
                x2 = tk ? ox : x2; y2 = tk ? oy : y2; z2 = tk ? oz : z2;
            }
            if (lane == 0) {
                s_bc[0] = __int_as_float(n2);
                s_bc[1] = x2; s_bc[2] = y2; s_bc[3] = z2;
            }
        }
        __syncthreads();
    }

    // ---- fused CNMS on wave 0 ----
    if (t < 64) {
        const float THR = (float)((2.0 * 0.1 * (1.0 - 0.7)) * (2.0 * 0.1 * (1.0 - 0.7)));
        float ax = s_cen[t][0],      ay = s_cen[t][1],      az = s_cen[t][2];
        float ex = s_cen[t + 64][0], ey = s_cen[t + 64][1], ez = s_cen[t + 64][2];
        bool k0 = false, k1 = false;
        for (int j = 0; j < G_; j++) {
            float jx = s_cen[j][0], jy = s_cen[j][1], jz = s_cen[j][2];
            bool c0 = k0 && (dist2(ax, ay, az, jx, jy, jz) < THR);
            bool c1 = k1 && (dist2(ex, ey, ez, jx, jy, jz) < THR);
            bool conflict = __any(c0 || c1);
            if (j == t)      k0 = !conflict;
            if (j == t + 64) k1 = !conflict;
        }
        keep_out[b * G_ + t]      = k0 ? 1 : 0;
        keep_out[b * G_ + t + 64] = k1 ? 1 : 0;
    }
}

// ---------------------------------------------------------------------------
// Kernel 2: per-(b,g) ball query (first 128 by index) + top-32 by energy +
// gather/normalize. One 256-thread block per group.
// ---------------------------------------------------------------------------
__global__ __launch_bounds__(BQ_T) void group_kernel(
    const float4* __restrict__ pts, const int* __restrict__ lengths,
    const float* __restrict__ centers, const int* __restrict__ keep,
    float* __restrict__ groups_out, int* __restrict__ gl) {
    const int bid = blockIdx.x;          // b*128 + g
    const int b = bid >> 7;
    const int t = threadIdx.x;
    const int lane = t & 63;
    const int wv = t >> 6;

    const float cx = centers[bid * 3 + 0];
    const float cy = centers[bid * 3 + 1];
    const float cz = centers[bid * 3 + 2];
    float4* out4 = (float4*)(groups_out + (size_t)bid * GS_ * 4);

    if (!keep[bid]) {
        // fidx == -1 everywhere: groups row = ((0-c)/0.1, 0)
        if (t < GS_) {
            float4 o;
            o.x = __fdiv_rn(__fsub_rn(0.f, cx), 0.1f);
            o.y = __fdiv_rn(__fsub_rn(0.f, cy), 0.1f);
            o.z = __fdiv_rn(__fsub_rn(0.f, cz), 0.1f);
            o.w = 0.f;
            out4[t] = o;
        }
        return;
    }

    __shared__ int   s_list[UK_];
    __shared__ float s_en[UK_];
    __shared__ int   s_wc[4];
    __shared__ int   s_ord[GS_];

    const int len = lengths[b];
    const float R2 = (float)(0.1 * 0.1);
    const float4* p = pts + (size_t)b * N_;

    int cnt = 0;
    for (int base = 0; base < N_; base += BQ_T) {
        int n = base + t;
        float4 q = p[n];
        float d2 = dist2(q.x, q.y, q.z, cx, cy, cz);
        bool pred = (n < len) && (d2 <= R2);
        unsigned long long m = __ballot(pred);
        int prefix = __popcll(m & ((1ull << lane) - 1ull));
        if (lane == 0) s_wc[wv] = __popcll(m);
        __syncthreads();
        int c0 = s_wc[0], c1 = s_wc[1], c2 = s_wc[2], c3 = s_wc[3];
        int off = cnt + (wv > 0 ? c0 : 0) + (wv > 1 ? c1 : 0) + (wv > 2 ? c2 : 0);
        int slot = off + prefix;
        if (pred && slot < UK_) { s_list[slot] = n; s_en[slot] = q.w; }
        cnt += c0 + c1 + c2 + c3;
        __syncthreads();
        if (cnt >= UK_) break;     // uniform
    }
    const int M = min(cnt, UK_);

    // top-32 by energy, tie -> smaller list position (matches lax.top_k)
    if (wv == 0) {
        float v0 = (lane < M) ? s_en[lane] : -INFINITY;
        float v1 = (lane + 64 < M) ? s_en[lane + 64] : -INFINITY;
        for (int k = 0; k < GS_; k++) {
            float bv; int bs;
            if (v0 >= v1) { bv = v0; bs = lane; }
            else          { bv = v1; bs = lane + 64; }
#pragma unroll
            for (int off = 32; off; off >>= 1) {
                float ov = __shfl_xor(bv, off);
                int   os = __shfl_xor(bs, off);
                bool tk = (ov > bv) || (ov == bv && os < bs);
                bv = tk ? ov : bv; bs = tk ? os : bs;
            }
            if (lane == 0) s_ord[k] = (bv == -INFINITY) ? -1 : bs;
            if (bs == lane)           v0 = -INFINITY;
            else if (bs == lane + 64) v1 = -INFINITY;
        }
    }
    __syncthreads();

    if (t < GS_) {
        int o0 = s_ord[0];
        int first = (o0 >= 0) ? s_list[o0] : -1;
        int ok = s_ord[t];
        int ti = (ok >= 0) ? s_list[ok] : -1;
        int f = (ti == -1) ? first : ti;
        float px = 0.f, py = 0.f, pz = 0.f, pw = 0.f;
        if (f >= 0) { float4 q = p[f]; px = q.x; py = q.y; pz = q.z; pw = q.w; }
        float4 o;
        o.x = __fdiv_rn(__fsub_rn(px, cx), 0.1f);
        o.y = __fdiv_rn(__fsub_rn(py, cy), 0.1f);
        o.z = __fdiv_rn(__fsub_rn(pz, cz), 0.1f);
        o.w = __fdiv_rn(pw, 0.1f);
        out4[t] = o;
    }
    if (t == 0 && M >= GS_) atomicAdd(&gl[b], 1);
}

// ---------------------------------------------------------------------------
// Kernel 3: embedding mask
// ---------------------------------------------------------------------------
__global__ void mask_kernel(const int* __restrict__ gl, float* __restrict__ mask_out) {
    int t = threadIdx.x;                 // 1024 threads
    int b = t >> 7, g = t & 127;
    mask_out[t] = (g < gl[b]) ? 1.0f : 0.0f;
}

extern "C" void kernel_launch(void* const* d_in, const int* in_sizes, int n_in,
                              void* d_out, int out_size, void* d_ws, size_t ws_size,
                              hipStream_t stream) {
    const float4* pts = (const float4*)d_in[0];
    const int* lengths = (const int*)d_in[1];
    float* out = (float*)d_out;
    float* groups = out;                          // B*G*GS*4 = 131072
    float* centers = out + (size_t)B_ * G_ * GS_ * 4;  // +3072
    float* mask = centers + (size_t)B_ * G_ * 3;       // +1024
    int* keep = (int*)d_ws;                       // B*G ints
    int* gl = keep + B_ * G_;                     // B ints

    hipMemsetAsync(gl, 0, B_ * sizeof(int), stream);
    hipLaunchKernelGGL(fps_cnms_kernel, dim3(B_), dim3(FPS_T), 0, stream,
                       pts, lengths, centers, keep);
    hipLaunchKernelGGL(group_kernel, dim3(B_ * G_), dim3(BQ_T), 0, stream,
                       pts, lengths, centers, keep, groups, gl);
    hipLaunchKernelGGL(mask_kernel, dim3(1), dim3(B_ * G_), 0, stream, gl, mask);
}

// Round 2
// 349.130 us; speedup vs baseline: 1.4210x; 1.4210x over previous
//
#include <hip/hip_runtime.h>
#include <math.h>

#define B_ 8
#define N_ 16384
#define G_ 128      // NUM_GROUPS
#define GS_ 32      // GROUP_SIZE
#define UK_ 128     // UPSCALE_K
#define FPS_T 512
#define FPS_W 8     // waves per FPS block
#define PPT 32      // points per thread in FPS (32*512 = 16384)
#define BQ_T 256

// Exact-rounding distance^2, matching numpy: ((dx*dx + dy*dy) + dz*dz), no FMA.
__device__ __forceinline__ float dist2(float x, float y, float z,
                                       float cx, float cy, float cz) {
    float dx = __fsub_rn(x, cx);
    float dy = __fsub_rn(y, cy);
    float dz = __fsub_rn(z, cz);
    return __fadd_rn(__fadd_rn(__fmul_rn(dx, dx), __fmul_rn(dy, dy)),
                     __fmul_rn(dz, dz));
}

__device__ __forceinline__ unsigned long long shfl_xor_u64(unsigned long long v, int m) {
    int lo = __shfl_xor((int)(unsigned)(v & 0xffffffffull), m);
    int hi = __shfl_xor((int)(unsigned)(v >> 32), m);
    return ((unsigned long long)(unsigned)hi << 32) | (unsigned)lo;
}

__device__ __forceinline__ unsigned long long umax64(unsigned long long a,
                                                     unsigned long long b) {
    return a > b ? a : b;
}

// ---------------------------------------------------------------------------
// Kernel 1: FPS (one block per batch) + fused cluster-NMS (wave 0 at the end).
// Argmax carried as a single u64 key: monotone(float) in hi32, ~idx in lo32,
// so unsigned max == (larger dist, tie -> smaller index).
// ---------------------------------------------------------------------------
__global__ __launch_bounds__(FPS_T) void fps_cnms_kernel(
    const float4* __restrict__ pts, const int* __restrict__ lengths,
    float* __restrict__ centers_out, int* __restrict__ keep_out) {
    const int b = blockIdx.x;
    const int t = threadIdx.x;
    const int lane = t & 63;
    const int wv = t >> 6;
    const int len = lengths[b];
    const float4* p = pts + (size_t)b * N_;

    // Register-resident point coords + running min-distance.
    float xs[PPT], ys[PPT], zs[PPT], mind[PPT];
#pragma unroll
    for (int i = 0; i < PPT; i++) {
        int n = i * FPS_T + t;
        float4 q = p[n];
        xs[i] = q.x; ys[i] = q.y; zs[i] = q.z;
        mind[i] = (n < len) ? INFINITY : -INFINITY;
    }

    __shared__ __align__(16) unsigned long long s_part[2][FPS_W];
    __shared__ float s_cen[G_][3];    // centers for CNMS

    int n = 0;   // winner index (uniform across block); first center is idx 0
    for (int k = 0; k < G_; k++) {
        float4 c = p[n];   // wave-uniform broadcast load (L1 hit)
        float cx = c.x, cy = c.y, cz = c.z;
        if (t == 0) {
            centers_out[(b * G_ + k) * 3 + 0] = cx;
            centers_out[(b * G_ + k) * 3 + 1] = cy;
            centers_out[(b * G_ + k) * 3 + 2] = cz;
            s_cen[k][0] = cx; s_cen[k][1] = cy; s_cen[k][2] = cz;
        }
        if (k == G_ - 1) break;   // last argmax is discarded by the reference

        // Local update + argmax tracking (strict > keeps earliest i => smallest n).
        float bv = -INFINITY;
        int bn = 0x7fffffff;
#pragma unroll
        for (int i = 0; i < PPT; i++) {
            float d = dist2(xs[i], ys[i], zs[i], cx, cy, cz);
            float m = fminf(mind[i], d);   // invalid stays -inf
            mind[i] = m;
            if (m > bv) { bv = m; bn = i * FPS_T + t; }
        }
        // Pack (bv, bn) into one monotone u64 key.
        unsigned u = __float_as_uint(bv);
        u = (u & 0x80000000u) ? ~u : (u | 0x80000000u);
        unsigned long long key =
            ((unsigned long long)u << 32) | (unsigned)(~bn);

        // Wave butterfly max (2 x b32 shuffle per level).
#pragma unroll
        for (int off = 32; off; off >>= 1)
            key = umax64(key, shfl_xor_u64(key, off));

        if (lane == 0) s_part[k & 1][wv] = key;
        __syncthreads();

        // Every thread reduces the 8 wave partials (2 x ds_read_b128).
        const ulonglong2* sp = (const ulonglong2*)s_part[k & 1];
        ulonglong2 a0 = sp[0], a1 = sp[1], a2 = sp[2], a3 = sp[3];
        unsigned long long w0 = umax64(umax64(a0.x, a0.y), umax64(a1.x, a1.y));
        unsigned long long w1 = umax64(umax64(a2.x, a2.y), umax64(a3.x, a3.y));
        key = umax64(w0, w1);
        n = (int)(~(unsigned)(key & 0xffffffffull));
    }

    // ---- fused CNMS on wave 0 (s_cen writes are by t0, same wave => ordered) ----
    if (t < 64) {
        const float THR = (float)((2.0 * 0.1 * (1.0 - 0.7)) * (2.0 * 0.1 * (1.0 - 0.7)));
        float ax = s_cen[t][0],      ay = s_cen[t][1],      az = s_cen[t][2];
        float ex = s_cen[t + 64][0], ey = s_cen[t + 64][1], ez = s_cen[t + 64][2];
        bool k0 = false, k1 = false;
        for (int j = 0; j < G_; j++) {
            float jx = s_cen[j][0], jy = s_cen[j][1], jz = s_cen[j][2];
            bool c0 = k0 && (dist2(ax, ay, az, jx, jy, jz) < THR);
            bool c1 = k1 && (dist2(ex, ey, ez, jx, jy, jz) < THR);
            bool conflict = __any(c0 || c1);
            if (j == t)      k0 = !conflict;
            if (j == t + 64) k1 = !conflict;
        }
        keep_out[b * G_ + t]      = k0 ? 1 : 0;
        keep_out[b * G_ + t + 64] = k1 ? 1 : 0;
    }
}

// ---------------------------------------------------------------------------
// Kernel 2: per-(b,g) ball query (first 128 by index) + top-32 by energy +
// gather/normalize. One 256-thread block per group. Each wave autonomously
// compacts its contiguous quarter of the index range (no in-loop barriers);
// ordered merge preserves first-128-by-global-index semantics.
// ---------------------------------------------------------------------------
__global__ __launch_bounds__(BQ_T) void group_kernel(
    const float4* __restrict__ pts, const int* __restrict__ lengths,
    const float* __restrict__ centers, const int* __restrict__ keep,
    float* __restrict__ groups_out, int* __restrict__ gl) {
    const int bid = blockIdx.x;          // b*128 + g
    const int b = bid >> 7;
    const int t = threadIdx.x;
    const int lane = t & 63;
    const int wv = t >> 6;

    const float cx = centers[bid * 3 + 0];
    const float cy = centers[bid * 3 + 1];
    const float cz = centers[bid * 3 + 2];
    float4* out4 = (float4*)(groups_out + (size_t)bid * GS_ * 4);

    if (!keep[bid]) {
        // fidx == -1 everywhere: groups row = ((0-c)/0.1, 0)
        if (t < GS_) {
            float4 o;
            o.x = __fdiv_rn(__fsub_rn(0.f, cx), 0.1f);
            o.y = __fdiv_rn(__fsub_rn(0.f, cy), 0.1f);
            o.z = __fdiv_rn(__fsub_rn(0.f, cz), 0.1f);
            o.w = 0.f;
            out4[t] = o;
        }
        return;
    }

    __shared__ int   s_widx[4][UK_];
    __shared__ float s_wen[4][UK_];
    __shared__ int   s_wcnt[4];
    __shared__ int   s_list[UK_];
    __shared__ float s_en[UK_];
    __shared__ int   s_ord[GS_];

    const int len = lengths[b];
    const float R2 = (float)(0.1 * 0.1);
    const float4* p = pts + (size_t)b * N_;

    // Per-wave ordered stream compaction over its contiguous quarter.
    {
        const int base0 = wv * (N_ / 4);
        int cnt = 0;
        for (int it = 0; it < (N_ / 4) / 64; it++) {
            int n = base0 + it * 64 + lane;
            float4 q = p[n];
            float d2 = dist2(q.x, q.y, q.z, cx, cy, cz);
            bool pred = (n < len) && (d2 <= R2);
            unsigned long long m = __ballot(pred);
            int prefix = __popcll(m & ((1ull << lane) - 1ull));
            int slot = cnt + prefix;
            if (pred && slot < UK_) { s_widx[wv][slot] = n; s_wen[wv][slot] = q.w; }
            cnt += __popcll(m);
            if (cnt >= UK_) break;      // wave-uniform
        }
        if (lane == 0) s_wcnt[wv] = (cnt < UK_) ? cnt : UK_;
    }
    __syncthreads();

    const int m0 = s_wcnt[0], m1 = s_wcnt[1], m2 = s_wcnt[2], m3 = s_wcnt[3];
    int M = m0 + m1 + m2 + m3;
    if (M > UK_) M = UK_;

    // Ordered merge into unified first-M list.
    if (t < UK_ && t < M) {
        int j = t, w = 0;
        if (j >= m0) { j -= m0; w = 1;
            if (j >= m1) { j -= m1; w = 2;
                if (j >= m2) { j -= m2; w = 3; } } }
        s_list[t] = s_widx[w][j];
        s_en[t]   = s_wen[w][j];
    }
    __syncthreads();

    // top-32 by energy, tie -> smaller list position (matches lax.top_k)
    if (wv == 0) {
        float v0 = (lane < M) ? s_en[lane] : -INFINITY;
        float v1 = (lane + 64 < M) ? s_en[lane + 64] : -INFINITY;
        for (int k = 0; k < GS_; k++) {
            float bv; int bs;
            if (v0 >= v1) { bv = v0; bs = lane; }
            else          { bv = v1; bs = lane + 64; }
#pragma unroll
            for (int off = 32; off; off >>= 1) {
                float ov = __shfl_xor(bv, off);
                int   os = __shfl_xor(bs, off);
                bool tk = (ov > bv) || (ov == bv && os < bs);
                bv = tk ? ov : bv; bs = tk ? os : bs;
            }
            if (lane == 0) s_ord[k] = (bv == -INFINITY) ? -1 : bs;
            if (bs == lane)           v0 = -INFINITY;
            else if (bs == lane + 64) v1 = -INFINITY;
        }
    }
    __syncthreads();

    if (t < GS_) {
        int o0 = s_ord[0];
        int first = (o0 >= 0) ? s_list[o0] : -1;
        int ok = s_ord[t];
        int ti = (ok >= 0) ? s_list[ok] : -1;
        int f = (ti == -1) ? first : ti;
        float px = 0.f, py = 0.f, pz = 0.f, pw = 0.f;
        if (f >= 0) { float4 q = p[f]; px = q.x; py = q.y; pz = q.z; pw = q.w; }
        float4 o;
        o.x = __fdiv_rn(__fsub_rn(px, cx), 0.1f);
        o.y = __fdiv_rn(__fsub_rn(py, cy), 0.1f);
        o.z = __fdiv_rn(__fsub_rn(pz, cz), 0.1f);
        o.w = __fdiv_rn(pw, 0.1f);
        out4[t] = o;
    }
    if (t == 0 && M >= GS_) atomicAdd(&gl[b], 1);
}

// ---------------------------------------------------------------------------
// Kernel 3: embedding mask
// ---------------------------------------------------------------------------
__global__ void mask_kernel(const int* __restrict__ gl, float* __restrict__ mask_out) {
    int t = threadIdx.x;                 // 1024 threads
    int b = t >> 7, g = t & 127;
    mask_out[t] = (g < gl[b]) ? 1.0f : 0.0f;
}

extern "C" void kernel_launch(void* const* d_in, const int* in_sizes, int n_in,
                              void* d_out, int out_size, void* d_ws, size_t ws_size,
                              hipStream_t stream) {
    const float4* pts = (const float4*)d_in[0];
    const int* lengths = (const int*)d_in[1];
    float* out = (float*)d_out;
    float* groups = out;                               // B*G*GS*4 = 131072
    float* centers = out + (size_t)B_ * G_ * GS_ * 4;  // +3072
    float* mask = centers + (size_t)B_ * G_ * 3;       // +1024
    int* keep = (int*)d_ws;                            // B*G ints
    int* gl = keep + B_ * G_;                          // B ints

    hipMemsetAsync(gl, 0, B_ * sizeof(int), stream);
    hipLaunchKernelGGL(fps_cnms_kernel, dim3(B_), dim3(FPS_T), 0, stream,
                       pts, lengths, centers, keep);
    hipLaunchKernelGGL(group_kernel, dim3(B_ * G_), dim3(BQ_T), 0, stream,
                       pts, lengths, centers, keep, groups, gl);
    hipLaunchKernelGGL(mask_kernel, dim3(1), dim3(B_ * G_), 0, stream, gl, mask);
}